// Round 1
// baseline (244.558 us; speedup 1.0000x reference)
//
#include <hip/hip_runtime.h>

typedef float  f32x4 __attribute__((ext_vector_type(4)));
typedef short  s16x8 __attribute__((ext_vector_type(8)));

#define ND   64     // node dim
#define DE   32     // edge dim
#define K1   160    // 2*ND + DE
#define K1P  168    // padded LDS stride (bf16 elems), 336B = 16B-aligned, 2-way banks
#define K2P  72     // padded stride for 64-wide tiles, 144B
#define KN   128    // node MLP input dim
#define KNP  136    // padded, 272B

__device__ __forceinline__ ushort f2bf(float f) {
  unsigned u = __float_as_uint(f);
  unsigned r = (u + 0x7fffu + ((u >> 16) & 1u)) >> 16;  // RNE
  return (ushort)r;
}
__device__ __forceinline__ float relu_f(float v) { return v > 0.f ? v : 0.f; }

// ---------------- edge kernel: gather -> MLP -> scatter-add ----------------
__launch_bounds__(256, 2)
__global__ void gc_edge(const float* __restrict__ x,
                        const int* __restrict__ eidx,     // [2][E]
                        const float* __restrict__ eattr,  // [E][32]
                        const float* __restrict__ W1e, const float* __restrict__ b1e,
                        const float* __restrict__ W2e, const float* __restrict__ b2e,
                        float* __restrict__ agg,
                        int E, int ntiles) {
  __shared__ ushort in_lds[64][K1P];   // 64 edges x 160 (bf16)
  __shared__ ushort w1t[ND][K1P];      // W1e transposed: [d][k]
  __shared__ ushort w2t[ND][K2P];      // W2e transposed
  __shared__ ushort h_lds[64][K2P];    // hidden
  __shared__ int    idx_lds[128];      // rows 0..63, cols 64..127

  const int t    = threadIdx.x;
  const int lane = t & 63;
  const int w    = t >> 6;
  const int l15  = lane & 15;
  const int lhi  = lane >> 4;

  // stage transposed bf16 weights once per block
  for (int i = t; i < K1 * ND; i += 256) w1t[i & 63][i >> 6] = f2bf(W1e[i]);
  for (int i = t; i < 64 * ND; i += 256) w2t[i & 63][i >> 6] = f2bf(W2e[i]);
  __syncthreads();

  const int strip = w * 16;
  const int ar    = strip + l15;   // A-fragment row
  const int k8    = lhi * 8;       // k sub-offset within a K=32 step

  for (int tile = blockIdx.x; tile < ntiles; tile += gridDim.x) {
    const int e0 = tile * 64;
    if (t < 128) {
      int e = e0 + (t & 63);
      if (e >= E) e = E - 1;
      idx_lds[t] = (t < 64) ? eidx[e] : eidx[E + e];
    }
    __syncthreads();

    // gather: 64 edges x 40 float4-chunks (16 x[row], 16 x[col], 8 attr)
    #pragma unroll
    for (int i = 0; i < 10; ++i) {
      int chunk = t + i * 256;
      int e = chunk / 40;
      int p = chunk - e * 40;
      const float* src; int k0;
      if (p < 16)      { src = x + idx_lds[e]      * ND + p * 4;        k0 = p * 4; }
      else if (p < 32) { src = x + idx_lds[64 + e] * ND + (p - 16) * 4; k0 = 64 + (p - 16) * 4; }
      else { int ee = e0 + e; if (ee >= E) ee = E - 1;
             src = eattr + ee * DE + (p - 32) * 4;                      k0 = 128 + (p - 32) * 4; }
      f32x4 v = *(const f32x4*)src;
      ushort* dst = &in_lds[e][k0];
      dst[0] = f2bf(v.x); dst[1] = f2bf(v.y); dst[2] = f2bf(v.z); dst[3] = f2bf(v.w);
    }
    __syncthreads();

    // GEMM1: [16e x 160] @ [160 x 64], K=32 steps x5
    f32x4 acc1[4] = {};
    #pragma unroll
    for (int ks = 0; ks < 5; ++ks) {
      s16x8 a = *(const s16x8*)&in_lds[ar][ks * 32 + k8];
      #pragma unroll
      for (int n = 0; n < 4; ++n) {
        s16x8 b = *(const s16x8*)&w1t[n * 16 + l15][ks * 32 + k8];
        acc1[n] = __builtin_amdgcn_mfma_f32_16x16x32_bf16(a, b, acc1[n], 0, 0, 0);
      }
    }
    #pragma unroll
    for (int n = 0; n < 4; ++n) {
      int d = n * 16 + l15;
      float bias = b1e[d];
      #pragma unroll
      for (int j = 0; j < 4; ++j)
        h_lds[strip + lhi * 4 + j][d] = f2bf(relu_f(acc1[n][j] + bias));
    }
    __syncthreads();

    // GEMM2: [16e x 64] @ [64 x 64]
    f32x4 acc2[4] = {};
    #pragma unroll
    for (int ks = 0; ks < 2; ++ks) {
      s16x8 a = *(const s16x8*)&h_lds[ar][ks * 32 + k8];
      #pragma unroll
      for (int n = 0; n < 4; ++n) {
        s16x8 b = *(const s16x8*)&w2t[n * 16 + l15][ks * 32 + k8];
        acc2[n] = __builtin_amdgcn_mfma_f32_16x16x32_bf16(a, b, acc2[n], 0, 0, 0);
      }
    }
    // scatter-add into agg[col]
    #pragma unroll
    for (int n = 0; n < 4; ++n) {
      int d = n * 16 + l15;
      float bias = b2e[d];
      #pragma unroll
      for (int j = 0; j < 4; ++j) {
        int er = strip + lhi * 4 + j;
        if (e0 + er < E)
          atomicAdd(&agg[idx_lds[64 + er] * ND + d], acc2[n][j] + bias);
      }
    }
    __syncthreads();
  }
}

// ---------------- node kernel: concat(x, agg) -> MLP -> residual ReLU ------
__launch_bounds__(256, 2)
__global__ void gc_node(const float* __restrict__ x,
                        const float* __restrict__ agg,
                        const float* __restrict__ W1n, const float* __restrict__ b1n,
                        const float* __restrict__ W2n, const float* __restrict__ b2n,
                        float* __restrict__ out, int N) {
  __shared__ ushort in_lds[64][KNP];
  __shared__ ushort w1t[ND][KNP];
  __shared__ ushort w2t[ND][K2P];
  __shared__ ushort h_lds[64][K2P];

  const int t    = threadIdx.x;
  const int lane = t & 63;
  const int w    = t >> 6;
  const int l15  = lane & 15;
  const int lhi  = lane >> 4;

  for (int i = t; i < KN * ND; i += 256) w1t[i & 63][i >> 6] = f2bf(W1n[i]);
  for (int i = t; i < 64 * ND; i += 256) w2t[i & 63][i >> 6] = f2bf(W2n[i]);

  const int n0 = blockIdx.x * 64;
  // stage 64 nodes x 32 float4 (16 from x, 16 from agg)
  #pragma unroll
  for (int i = 0; i < 8; ++i) {
    int chunk = t + i * 256;
    int nl = chunk >> 5;
    int p  = chunk & 31;
    int node = n0 + nl; if (node >= N) node = N - 1;
    const float* src; int k0;
    if (p < 16) { src = x   + node * ND + p * 4;        k0 = p * 4; }
    else        { src = agg + node * ND + (p - 16) * 4; k0 = 64 + (p - 16) * 4; }
    f32x4 v = *(const f32x4*)src;
    ushort* dst = &in_lds[nl][k0];
    dst[0] = f2bf(v.x); dst[1] = f2bf(v.y); dst[2] = f2bf(v.z); dst[3] = f2bf(v.w);
  }
  __syncthreads();

  const int strip = w * 16;
  const int ar    = strip + l15;
  const int k8    = lhi * 8;

  f32x4 acc1[4] = {};
  #pragma unroll
  for (int ks = 0; ks < 4; ++ks) {
    s16x8 a = *(const s16x8*)&in_lds[ar][ks * 32 + k8];
    #pragma unroll
    for (int n = 0; n < 4; ++n) {
      s16x8 b = *(const s16x8*)&w1t[n * 16 + l15][ks * 32 + k8];
      acc1[n] = __builtin_amdgcn_mfma_f32_16x16x32_bf16(a, b, acc1[n], 0, 0, 0);
    }
  }
  #pragma unroll
  for (int n = 0; n < 4; ++n) {
    int d = n * 16 + l15;
    float bias = b1n[d];
    #pragma unroll
    for (int j = 0; j < 4; ++j)
      h_lds[strip + lhi * 4 + j][d] = f2bf(relu_f(acc1[n][j] + bias));
  }
  __syncthreads();

  f32x4 acc2[4] = {};
  #pragma unroll
  for (int ks = 0; ks < 2; ++ks) {
    s16x8 a = *(const s16x8*)&h_lds[ar][ks * 32 + k8];
    #pragma unroll
    for (int n = 0; n < 4; ++n) {
      s16x8 b = *(const s16x8*)&w2t[n * 16 + l15][ks * 32 + k8];
      acc2[n] = __builtin_amdgcn_mfma_f32_16x16x32_bf16(a, b, acc2[n], 0, 0, 0);
    }
  }
  #pragma unroll
  for (int n = 0; n < 4; ++n) {
    int d = n * 16 + l15;
    float bias = b2n[d];
    #pragma unroll
    for (int j = 0; j < 4; ++j) {
      int node = n0 + strip + lhi * 4 + j;
      if (node < N) {
        float xv = x[node * ND + d];
        out[node * ND + d] = relu_f(acc2[n][j] + bias + xv);
      }
    }
  }
}

extern "C" void kernel_launch(void* const* d_in, const int* in_sizes, int n_in,
                              void* d_out, int out_size, void* d_ws, size_t ws_size,
                              hipStream_t stream) {
  const float* x     = (const float*)d_in[0];
  const int*   eidx  = (const int*)d_in[1];
  const float* eattr = (const float*)d_in[2];
  const float* W1e   = (const float*)d_in[3];
  const float* b1e   = (const float*)d_in[4];
  const float* W2e   = (const float*)d_in[5];
  const float* b2e   = (const float*)d_in[6];
  const float* W1n   = (const float*)d_in[7];
  const float* b1n   = (const float*)d_in[8];
  const float* W2n   = (const float*)d_in[9];
  const float* b2n   = (const float*)d_in[10];
  float* out = (float*)d_out;
  float* agg = (float*)d_ws;

  const int N = in_sizes[0] / ND;     // 50000
  const int E = in_sizes[1] / 2;      // 800000
  const int ntiles = (E + 63) / 64;

  hipMemsetAsync(agg, 0, (size_t)N * ND * sizeof(float), stream);

  int grid_e = ntiles < 1024 ? ntiles : 1024;
  gc_edge<<<grid_e, 256, 0, stream>>>(x, eidx, eattr, W1e, b1e, W2e, b2e, agg, E, ntiles);

  int grid_n = (N + 63) / 64;
  gc_node<<<grid_n, 256, 0, stream>>>(x, agg, W1n, b1n, W2n, b2n, out, N);
}

// Round 2
// 244.149 us; speedup vs baseline: 1.0017x; 1.0017x over previous
//
#include <hip/hip_runtime.h>

typedef float  f32x4 __attribute__((ext_vector_type(4)));
typedef short  s16x8 __attribute__((ext_vector_type(8)));

#define ND   64     // node dim
#define DE   32     // edge dim
#define K1   160    // 2*ND + DE
#define K1P  168    // padded LDS stride (bf16 elems); 84 dwords -> 2-way bank max
#define K2P  72     // padded stride for 64-wide tiles
#define KN   128    // node MLP input dim
#define KNP  136    // padded

__device__ __forceinline__ ushort f2bf(float f) {
  unsigned u = __float_as_uint(f);
  unsigned r = (u + 0x7fffu + ((u >> 16) & 1u)) >> 16;  // RNE
  return (ushort)r;
}
__device__ __forceinline__ float relu_f(float v) { return v > 0.f ? v : 0.f; }
__device__ __forceinline__ unsigned cvtpk(float lo, float hi) {
  unsigned r;
  asm("v_cvt_pk_bf16_f32 %0, %1, %2" : "=v"(r) : "v"(lo), "v"(hi));
  return r;
}
union PkFrag { unsigned u[4]; s16x8 v; };

// ---- edge kernel: per-wave 16 edges, gather->GEMM1->ReLU->scatter h -------
__launch_bounds__(256, 4)
__global__ void gc_edge(const float* __restrict__ x,
                        const int* __restrict__ eidx,     // [2][E]
                        const float* __restrict__ eattr,  // [E][32]
                        const float* __restrict__ W1e, const float* __restrict__ b1e,
                        float* __restrict__ hsum, float* __restrict__ deg,
                        int E, int ngroups) {
  __shared__ ushort w1t[ND][K1P];   // W1e transposed: [d][k]

  const int t    = threadIdx.x;
  const int lane = t & 63;
  const int w    = t >> 6;
  const int l15  = lane & 15;
  const int lhi  = lane >> 4;
  const int k8   = lhi * 8;

  for (int i = t; i < K1 * ND; i += 256) w1t[i & 63][i >> 6] = f2bf(W1e[i]);
  __syncthreads();

  float bias[4];
  #pragma unroll
  for (int n = 0; n < 4; ++n) bias[n] = b1e[n * 16 + l15];

  const int wid = blockIdx.x * 4 + w;
  const int nw  = gridDim.x * 4;

  for (int g = wid; g < ngroups; g += nw) {
    const int e = g * 16 + l15;            // this lane's edge (E % 16 == 0)
    const int rowi = eidx[e];
    const int coli = eidx[E + e];

    const f32x4* pr = (const f32x4*)(x + (size_t)rowi * ND);
    const f32x4* pc = (const f32x4*)(x + (size_t)coli * ND);
    const f32x4* pa = (const f32x4*)(eattr + (size_t)e * DE);
    const int q = lhi * 2;
    // issue all gathers up front (independent)
    f32x4 v0 = pr[q], v1 = pr[q + 1], v2 = pr[q + 8], v3 = pr[q + 9];
    f32x4 v4 = pc[q], v5 = pc[q + 1], v6 = pc[q + 8], v7 = pc[q + 9];
    f32x4 v8 = pa[q], v9 = pa[q + 1];

    PkFrag a[5];
    const f32x4 lo[5] = {v0, v2, v4, v6, v8};
    const f32x4 hi[5] = {v1, v3, v5, v7, v9};
    #pragma unroll
    for (int ks = 0; ks < 5; ++ks) {
      a[ks].u[0] = cvtpk(lo[ks].x, lo[ks].y);
      a[ks].u[1] = cvtpk(lo[ks].z, lo[ks].w);
      a[ks].u[2] = cvtpk(hi[ks].x, hi[ks].y);
      a[ks].u[3] = cvtpk(hi[ks].z, hi[ks].w);
    }

    f32x4 acc[4] = {};
    #pragma unroll
    for (int ks = 0; ks < 5; ++ks) {
      #pragma unroll
      for (int n = 0; n < 4; ++n) {
        s16x8 b = *(const s16x8*)&w1t[n * 16 + l15][ks * 32 + k8];
        acc[n] = __builtin_amdgcn_mfma_f32_16x16x32_bf16(a[ks].v, b, acc[n], 0, 0, 0);
      }
    }

    if (lhi == 0) atomicAdd(&deg[coli], 1.0f);   // one per edge

    #pragma unroll
    for (int j = 0; j < 4; ++j) {
      int sc = __shfl(coli, lhi * 4 + j, 64);    // col idx of edge lhi*4+j
      float* dst = hsum + (size_t)sc * ND;
      #pragma unroll
      for (int n = 0; n < 4; ++n)
        atomicAdd(&dst[n * 16 + l15], relu_f(acc[n][j] + bias[n]));
    }
  }
}

// ---- node kernel: agg = hsum@W2e + deg*b2e; then node MLP + residual ------
__launch_bounds__(256, 2)
__global__ void gc_node(const float* __restrict__ x,
                        const float* __restrict__ hsum,
                        const float* __restrict__ deg,
                        const float* __restrict__ W2e, const float* __restrict__ b2e,
                        const float* __restrict__ W1n, const float* __restrict__ b1n,
                        const float* __restrict__ W2n, const float* __restrict__ b2n,
                        float* __restrict__ out, int N) {
  __shared__ ushort w2et[ND][K2P];
  __shared__ ushort w1nt[ND][KNP];
  __shared__ ushort w2nt[ND][K2P];
  __shared__ ushort in_lds[64][KNP];
  __shared__ ushort h_lds[64][K2P];

  const int t    = threadIdx.x;
  const int lane = t & 63;
  const int w    = t >> 6;
  const int l15  = lane & 15;
  const int lhi  = lane >> 4;
  const int k8   = lhi * 8;

  for (int i = t; i < 64 * ND; i += 256) w2et[i & 63][i >> 6] = f2bf(W2e[i]);
  for (int i = t; i < KN * ND; i += 256) w1nt[i & 63][i >> 6] = f2bf(W1n[i]);
  for (int i = t; i < 64 * ND; i += 256) w2nt[i & 63][i >> 6] = f2bf(W2n[i]);

  const int n0 = blockIdx.x * 64;
  // stage x rows (bf16) into in_lds[:, 0:64]
  #pragma unroll
  for (int i = 0; i < 4; ++i) {
    int chunk = t + i * 256;        // 1024 = 64 rows x 16 f32x4
    int r = chunk >> 4, p = chunk & 15;
    int node = n0 + r; if (node >= N) node = N - 1;
    f32x4 v = *(const f32x4*)(x + (size_t)node * ND + p * 4);
    unsigned* dst = (unsigned*)&in_lds[r][p * 4];
    dst[0] = cvtpk(v.x, v.y); dst[1] = cvtpk(v.z, v.w);
  }

  const int strip = w * 16;
  // GEMM-A: agg rows for this wave
  {
    int arow = strip + l15;
    int node = n0 + arow; if (node >= N) node = N - 1;
    const f32x4* ph = (const f32x4*)(hsum + (size_t)node * ND);
    const int q = lhi * 2;
    f32x4 u0 = ph[q], u1 = ph[q + 1], u2 = ph[q + 8], u3 = ph[q + 9];
    PkFrag a0, a1;
    a0.u[0] = cvtpk(u0.x, u0.y); a0.u[1] = cvtpk(u0.z, u0.w);
    a0.u[2] = cvtpk(u1.x, u1.y); a0.u[3] = cvtpk(u1.z, u1.w);
    a1.u[0] = cvtpk(u2.x, u2.y); a1.u[1] = cvtpk(u2.z, u2.w);
    a1.u[2] = cvtpk(u3.x, u3.y); a1.u[3] = cvtpk(u3.z, u3.w);
    __syncthreads();   // weights + x staging visible
    f32x4 accg[4] = {};
    #pragma unroll
    for (int n = 0; n < 4; ++n) {
      s16x8 b0 = *(const s16x8*)&w2et[n * 16 + l15][k8];
      s16x8 b1 = *(const s16x8*)&w2et[n * 16 + l15][32 + k8];
      accg[n] = __builtin_amdgcn_mfma_f32_16x16x32_bf16(a0.v, b0, accg[n], 0, 0, 0);
      accg[n] = __builtin_amdgcn_mfma_f32_16x16x32_bf16(a1.v, b1, accg[n], 0, 0, 0);
    }
    #pragma unroll
    for (int n = 0; n < 4; ++n) {
      int d = n * 16 + l15;
      float b2 = b2e[d];
      #pragma unroll
      for (int j = 0; j < 4; ++j) {
        int r = strip + lhi * 4 + j;
        int node2 = n0 + r; if (node2 >= N) node2 = N - 1;
        float ag = accg[n][j] + deg[node2] * b2;
        in_lds[r][64 + d] = f2bf(ag);
      }
    }
  }
  __syncthreads();

  // GEMM1n: [64 x 128] @ [128 x 64]
  const int ar = strip + l15;
  f32x4 acc1[4] = {};
  #pragma unroll
  for (int ks = 0; ks < 4; ++ks) {
    s16x8 a = *(const s16x8*)&in_lds[ar][ks * 32 + k8];
    #pragma unroll
    for (int n = 0; n < 4; ++n) {
      s16x8 b = *(const s16x8*)&w1nt[n * 16 + l15][ks * 32 + k8];
      acc1[n] = __builtin_amdgcn_mfma_f32_16x16x32_bf16(a, b, acc1[n], 0, 0, 0);
    }
  }
  #pragma unroll
  for (int n = 0; n < 4; ++n) {
    int d = n * 16 + l15;
    float bias = b1n[d];
    #pragma unroll
    for (int j = 0; j < 4; ++j)
      h_lds[strip + lhi * 4 + j][d] = f2bf(relu_f(acc1[n][j] + bias));
  }
  __syncthreads();

  // GEMM2n + residual
  f32x4 acc2[4] = {};
  #pragma unroll
  for (int ks = 0; ks < 2; ++ks) {
    s16x8 a = *(const s16x8*)&h_lds[ar][ks * 32 + k8];
    #pragma unroll
    for (int n = 0; n < 4; ++n) {
      s16x8 b = *(const s16x8*)&w2nt[n * 16 + l15][ks * 32 + k8];
      acc2[n] = __builtin_amdgcn_mfma_f32_16x16x32_bf16(a, b, acc2[n], 0, 0, 0);
    }
  }
  #pragma unroll
  for (int n = 0; n < 4; ++n) {
    int d = n * 16 + l15;
    float bias = b2n[d];
    #pragma unroll
    for (int j = 0; j < 4; ++j) {
      int node = n0 + strip + lhi * 4 + j;
      if (node < N) {
        float xv = x[(size_t)node * ND + d];
        out[(size_t)node * ND + d] = relu_f(acc2[n][j] + bias + xv);
      }
    }
  }
}

extern "C" void kernel_launch(void* const* d_in, const int* in_sizes, int n_in,
                              void* d_out, int out_size, void* d_ws, size_t ws_size,
                              hipStream_t stream) {
  const float* x     = (const float*)d_in[0];
  const int*   eidx  = (const int*)d_in[1];
  const float* eattr = (const float*)d_in[2];
  const float* W1e   = (const float*)d_in[3];
  const float* b1e   = (const float*)d_in[4];
  const float* W2e   = (const float*)d_in[5];
  const float* b2e   = (const float*)d_in[6];
  const float* W1n   = (const float*)d_in[7];
  const float* b1n   = (const float*)d_in[8];
  const float* W2n   = (const float*)d_in[9];
  const float* b2n   = (const float*)d_in[10];
  float* out = (float*)d_out;

  const int N = in_sizes[0] / ND;     // 50000
  const int E = in_sizes[1] / 2;      // 800000
  const int ngroups = E / 16;         // E % 16 == 0

  float* hsum = (float*)d_ws;                       // [N][64]
  float* deg  = hsum + (size_t)N * ND;              // [N]

  hipMemsetAsync(d_ws, 0, ((size_t)N * ND + N) * sizeof(float), stream);

  gc_edge<<<2048, 256, 0, stream>>>(x, eidx, eattr, W1e, b1e, hsum, deg, E, ngroups);

  int grid_n = (N + 63) / 64;
  gc_node<<<grid_n, 256, 0, stream>>>(x, hsum, deg, W2e, b2e, W1n, b1n, W2n, b2n, out, N);
}

// Round 3
// 167.697 us; speedup vs baseline: 1.4583x; 1.4559x over previous
//
#include <hip/hip_runtime.h>

typedef float    f32x4 __attribute__((ext_vector_type(4)));
typedef short    s16x8 __attribute__((ext_vector_type(8)));
typedef unsigned u32x2 __attribute__((ext_vector_type(2)));

#define ND   64     // node dim
#define DE   32     // edge dim
#define K1   160    // 2*ND + DE
#define K1P  168    // LDS row stride (bf16): 336B, 16B-aligned, 2-way banks max
#define K2P  72
#define KN   128
#define KNP  136

__device__ __forceinline__ ushort f2bf(float f) {
  unsigned u = __float_as_uint(f);
  return (ushort)((u + 0x7fffu + ((u >> 16) & 1u)) >> 16);  // RNE
}
__device__ __forceinline__ float relu_f(float v) { return v > 0.f ? v : 0.f; }
__device__ __forceinline__ unsigned cvtpk(float lo, float hi) {
  unsigned r;
  asm("v_cvt_pk_bf16_f32 %0, %1, %2" : "=v"(r) : "v"(lo), "v"(hi));
  return r;
}

// ---- edge kernel: cooperative gather -> GEMM1 -> ReLU -> pk_bf16 scatter ---
__launch_bounds__(256, 3)
__global__ void gc_edge(const float* __restrict__ x,
                        const int* __restrict__ eidx,     // [2][E]
                        const float* __restrict__ eattr,  // [E][32]
                        const float* __restrict__ W1e, const float* __restrict__ b1e,
                        ushort* __restrict__ hsum,        // [N][64] bf16
                        float* __restrict__ deg,
                        int E, int ngroups) {
  __shared__ ushort   w1t[ND][K1P];        // W1e transposed [d][k]
  __shared__ ushort   strip[4][16][K1P];   // per-wave staging: 16 edges x 160
  __shared__ unsigned hb[4][16][33];       // per-wave packed-bf16 h rows

  const int t    = threadIdx.x;
  const int lane = t & 63;
  const int w    = t >> 6;
  const int l15  = lane & 15;
  const int lhi  = lane >> 4;
  const int k8   = lhi * 8;

  for (int i = t; i < K1 * ND; i += 256) w1t[i & 63][i >> 6] = f2bf(W1e[i]);
  __syncthreads();

  float bias[4];
  #pragma unroll
  for (int n = 0; n < 4; ++n) bias[n] = b1e[n * 16 + l15];

  const int el   = lane >> 2;          // edge this lane helps gather (0..15)
  const int part = lane & 3;           // 16B quarter-of-64B within row chunk
  const int wid  = blockIdx.x * 4 + w;
  const int nw   = gridDim.x * 4;

  for (int g = wid; g < ngroups; g += nw) {
    const int e0 = g * 16;
    int myidx = 0;
    if (lane < 32)
      myidx = (lane < 16) ? eidx[e0 + lane] : eidx[E + e0 + (lane - 16)];

    const int rrow = __shfl(myidx, el);
    const int rcol = __shfl(myidx, 16 + el);
    const float* xr = x + (size_t)rrow * ND + part * 4;
    const float* xc = x + (size_t)rcol * ND + part * 4;
    const float* ap = eattr + ((size_t)e0 + (lane >> 3)) * DE + (lane & 7) * 4;

    f32x4 vr[4], vc[4], va[2];
    #pragma unroll
    for (int i = 0; i < 4; ++i) vr[i] = *(const f32x4*)(xr + i * 16);
    #pragma unroll
    for (int i = 0; i < 4; ++i) vc[i] = *(const f32x4*)(xc + i * 16);
    va[0] = *(const f32x4*)ap;
    va[1] = *(const f32x4*)(ap + 8 * DE);

    // stage to this wave's strip (bf16)
    #pragma unroll
    for (int i = 0; i < 4; ++i) {
      u32x2 d = { cvtpk(vr[i].x, vr[i].y), cvtpk(vr[i].z, vr[i].w) };
      *(u32x2*)&strip[w][el][i * 16 + part * 4] = d;
    }
    #pragma unroll
    for (int i = 0; i < 4; ++i) {
      u32x2 d = { cvtpk(vc[i].x, vc[i].y), cvtpk(vc[i].z, vc[i].w) };
      *(u32x2*)&strip[w][el][64 + i * 16 + part * 4] = d;
    }
    #pragma unroll
    for (int i = 0; i < 2; ++i) {
      u32x2 d = { cvtpk(va[i].x, va[i].y), cvtpk(va[i].z, va[i].w) };
      *(u32x2*)&strip[w][(lane >> 3) + i * 8][128 + (lane & 7) * 4] = d;
    }
    asm volatile("s_waitcnt lgkmcnt(0)" ::: "memory");   // wave-local drain

    // GEMM1: [16 x 160] @ [160 x 64]
    f32x4 acc[4] = {};
    #pragma unroll
    for (int ks = 0; ks < 5; ++ks) {
      s16x8 a = *(const s16x8*)&strip[w][l15][ks * 32 + k8];
      #pragma unroll
      for (int n = 0; n < 4; ++n) {
        s16x8 b = *(const s16x8*)&w1t[n * 16 + l15][ks * 32 + k8];
        acc[n] = __builtin_amdgcn_mfma_f32_16x16x32_bf16(a, b, acc[n], 0, 0, 0);
      }
    }

    if (lane >= 16 && lane < 32) atomicAdd(&deg[myidx], 1.0f);

    // pack h rows (ReLU'd, bf16 pairs) into hb
    #pragma unroll
    for (int n = 0; n < 4; ++n) {
      #pragma unroll
      for (int j = 0; j < 4; ++j) {
        float r = relu_f(acc[n][j] + bias[n]);
        float p = __shfl_xor(r, 1);
        if (!(l15 & 1)) hb[w][lhi * 4 + j][(n * 16 + l15) >> 1] = cvtpk(r, p);
      }
    }
    asm volatile("s_waitcnt lgkmcnt(0)" ::: "memory");

    // scatter: 8 instrs, each = 4 edge-rows x full 64B line
    #pragma unroll
    for (int i = 0; i < 8; ++i) {
      int ee = (lane >> 4) + (i >> 1) * 4;
      int q  = (lane & 15) + (i & 1) * 16;
      int sc = __shfl(myidx, 16 + ee);
      uint64_t ad = (uint64_t)((unsigned*)hsum + (size_t)sc * 32 + q);
      unsigned data = hb[w][ee][q];
      asm volatile("global_atomic_pk_add_bf16 %0, %1, off" :: "v"(ad), "v"(data) : "memory");
    }
  }
}

// ---- node kernel: agg = hsum@W2e + deg*b2e; node MLP + residual ----------
__launch_bounds__(256, 2)
__global__ void gc_node(const float* __restrict__ x,
                        const ushort* __restrict__ hsum,   // bf16
                        const float* __restrict__ deg,
                        const float* __restrict__ W2e, const float* __restrict__ b2e,
                        const float* __restrict__ W1n, const float* __restrict__ b1n,
                        const float* __restrict__ W2n, const float* __restrict__ b2n,
                        float* __restrict__ out, int N) {
  __shared__ ushort w2et[ND][K2P];
  __shared__ ushort w1nt[ND][KNP];
  __shared__ ushort w2nt[ND][K2P];
  __shared__ ushort in_lds[64][KNP];
  __shared__ ushort h_lds[64][K2P];

  const int t    = threadIdx.x;
  const int lane = t & 63;
  const int w    = t >> 6;
  const int l15  = lane & 15;
  const int lhi  = lane >> 4;
  const int k8   = lhi * 8;

  for (int i = t; i < 64 * ND; i += 256) w2et[i & 63][i >> 6] = f2bf(W2e[i]);
  for (int i = t; i < KN * ND; i += 256) w1nt[i & 63][i >> 6] = f2bf(W1n[i]);
  for (int i = t; i < 64 * ND; i += 256) w2nt[i & 63][i >> 6] = f2bf(W2n[i]);

  const int n0 = blockIdx.x * 64;
  #pragma unroll
  for (int i = 0; i < 4; ++i) {
    int chunk = t + i * 256;
    int r = chunk >> 4, p = chunk & 15;
    int node = n0 + r; if (node >= N) node = N - 1;
    f32x4 v = *(const f32x4*)(x + (size_t)node * ND + p * 4);
    unsigned* dst = (unsigned*)&in_lds[r][p * 4];
    dst[0] = cvtpk(v.x, v.y); dst[1] = cvtpk(v.z, v.w);
  }

  const int strip = w * 16;
  {
    int arow = strip + l15;
    int node = n0 + arow; if (node >= N) node = N - 1;
    const s16x8* ph = (const s16x8*)(hsum + (size_t)node * ND);
    s16x8 a0 = ph[lhi];       // k = lhi*8
    s16x8 a1 = ph[4 + lhi];   // k = 32 + lhi*8
    __syncthreads();
    f32x4 accg[4] = {};
    #pragma unroll
    for (int n = 0; n < 4; ++n) {
      s16x8 b0 = *(const s16x8*)&w2et[n * 16 + l15][k8];
      s16x8 b1 = *(const s16x8*)&w2et[n * 16 + l15][32 + k8];
      accg[n] = __builtin_amdgcn_mfma_f32_16x16x32_bf16(a0, b0, accg[n], 0, 0, 0);
      accg[n] = __builtin_amdgcn_mfma_f32_16x16x32_bf16(a1, b1, accg[n], 0, 0, 0);
    }
    #pragma unroll
    for (int n = 0; n < 4; ++n) {
      int d = n * 16 + l15;
      float b2 = b2e[d];
      #pragma unroll
      for (int j = 0; j < 4; ++j) {
        int r = strip + lhi * 4 + j;
        int node2 = n0 + r; if (node2 >= N) node2 = N - 1;
        float ag = accg[n][j] + deg[node2] * b2;
        in_lds[r][64 + d] = f2bf(ag);
      }
    }
  }
  __syncthreads();

  const int ar = strip + l15;
  f32x4 acc1[4] = {};
  #pragma unroll
  for (int ks = 0; ks < 4; ++ks) {
    s16x8 a = *(const s16x8*)&in_lds[ar][ks * 32 + k8];
    #pragma unroll
    for (int n = 0; n < 4; ++n) {
      s16x8 b = *(const s16x8*)&w1nt[n * 16 + l15][ks * 32 + k8];
      acc1[n] = __builtin_amdgcn_mfma_f32_16x16x32_bf16(a, b, acc1[n], 0, 0, 0);
    }
  }
  #pragma unroll
  for (int n = 0; n < 4; ++n) {
    int d = n * 16 + l15;
    float bias = b1n[d];
    #pragma unroll
    for (int j = 0; j < 4; ++j)
      h_lds[strip + lhi * 4 + j][d] = f2bf(relu_f(acc1[n][j] + bias));
  }
  __syncthreads();

  f32x4 acc2[4] = {};
  #pragma unroll
  for (int ks = 0; ks < 2; ++ks) {
    s16x8 a = *(const s16x8*)&h_lds[ar][ks * 32 + k8];
    #pragma unroll
    for (int n = 0; n < 4; ++n) {
      s16x8 b = *(const s16x8*)&w2nt[n * 16 + l15][ks * 32 + k8];
      acc2[n] = __builtin_amdgcn_mfma_f32_16x16x32_bf16(a, b, acc2[n], 0, 0, 0);
    }
  }
  #pragma unroll
  for (int n = 0; n < 4; ++n) {
    int d = n * 16 + l15;
    float bias = b2n[d];
    #pragma unroll
    for (int j = 0; j < 4; ++j) {
      int node = n0 + strip + lhi * 4 + j;
      if (node < N) {
        float xv = x[(size_t)node * ND + d];
        out[(size_t)node * ND + d] = relu_f(acc2[n][j] + bias + xv);
      }
    }
  }
}

extern "C" void kernel_launch(void* const* d_in, const int* in_sizes, int n_in,
                              void* d_out, int out_size, void* d_ws, size_t ws_size,
                              hipStream_t stream) {
  const float* x     = (const float*)d_in[0];
  const int*   eidx  = (const int*)d_in[1];
  const float* eattr = (const float*)d_in[2];
  const float* W1e   = (const float*)d_in[3];
  const float* b1e   = (const float*)d_in[4];
  const float* W2e   = (const float*)d_in[5];
  const float* b2e   = (const float*)d_in[6];
  const float* W1n   = (const float*)d_in[7];
  const float* b1n   = (const float*)d_in[8];
  const float* W2n   = (const float*)d_in[9];
  const float* b2n   = (const float*)d_in[10];
  float* out = (float*)d_out;

  const int N = in_sizes[0] / ND;     // 50000
  const int E = in_sizes[1] / 2;      // 800000
  const int ngroups = E / 16;

  ushort* hsum = (ushort*)d_ws;                        // [N][64] bf16
  float*  degp = (float*)(hsum + (size_t)N * ND);      // [N]

  hipMemsetAsync(d_ws, 0, (size_t)N * ND * 2 + (size_t)N * 4, stream);

  gc_edge<<<2048, 256, 0, stream>>>(x, eidx, eattr, W1e, b1e, hsum, degp, E, ngroups);

  int grid_n = (N + 63) / 64;
  gc_node<<<grid_n, 256, 0, stream>>>(x, hsum, degp, W2e, b2e, W1n, b1n, W2n, b2n, out, N);
}